// Round 3
// baseline (195.030 us; speedup 1.0000x reference)
//
#include <hip/hip_runtime.h>
#include <hip/hip_fp16.h>

// MLP_52759378264652: x[B,2] -> Linear(2,4)+ReLU -> 98x(Linear(4,4)+Sigmoid)
//                     -> Linear(4,1). B = 1048576. fp32 in/out.
//
// R1 post-mortem: fp32 kernel was exactly at the VALU-issue roofline with
// trans (v_exp/v_rcp, 16cy/wave64) = 76% of issue cycles. R2/R3: all mid-layer
// math in packed f16 (v_pk_fma_f16, 2cy for 2 values), sigmoid as full-rate
// bit-trick exp2 + Newton rcp — zero transcendentals. Weights prescaled by
// -log2(e) and packed to half2 pairs in d_ws.
// R3 fix: ROCm 7.2 lacks __hmax2/__hmin2/__hneg2 -> inline asm v_pk_max/min
// and sign-bit XOR.

#define NMID 98
#define LSTRIDE 16  // u32 slots per layer in ws (10 used; padded for alignment)

union HU { unsigned u; __half2 h; };

__device__ __forceinline__ __half2 pk_max(__half2 a, __half2 b) {
    HU x, y, r; x.h = a; y.h = b;
    asm("v_pk_max_f16 %0, %1, %2" : "=v"(r.u) : "v"(x.u), "v"(y.u));
    return r.h;
}
__device__ __forceinline__ __half2 pk_min(__half2 a, __half2 b) {
    HU x, y, r; x.h = a; y.h = b;
    asm("v_pk_min_f16 %0, %1, %2" : "=v"(r.u) : "v"(x.u), "v"(y.u));
    return r.h;
}
__device__ __forceinline__ __half2 pk_neg(__half2 a) {
    HU x; x.h = a; x.u ^= 0x80008000u;
    return x.h;
}

__global__ __launch_bounds__(256) void prep_kernel(
        const float* __restrict__ Wm, const float* __restrict__ bm,
        unsigned* __restrict__ ws) {
    int e = blockIdx.x * blockDim.x + threadIdx.x;
    if (e >= NMID * 10) return;
    int l = e / 10;
    int s = e - l * 10;
    const float c = -1.44269504088896340736f;  // -log2(e)
    float lo, hi;
    if (s < 4)       { lo = Wm[l*16 + 0*4 + s];      hi = Wm[l*16 + 1*4 + s]; }
    else if (s < 8)  { int k = s - 4;
                       lo = Wm[l*16 + 2*4 + k];      hi = Wm[l*16 + 3*4 + k]; }
    else if (s == 8) { lo = bm[l*4 + 0];             hi = bm[l*4 + 1]; }
    else             { lo = bm[l*4 + 2];             hi = bm[l*4 + 3]; }
    HU q; q.h = __floats2half2_rn(c * lo, c * hi);
    ws[l * LSTRIDE + s] = q.u;
}

// sigmoid pair from prescaled y = -log2(e)*x : returns 1/(1+2^y), all full-rate.
__device__ __forceinline__ __half2 sigmoid2_from_y(__half2 y) {
    const __half2 kLo   = __float2half2_rn(-13.5f);
    const __half2 kHi   = __float2half2_rn( 13.5f);
    const __half2 k1536 = __float2half2_rn(1536.0f);
    const __half2 kC1   = __float2half2_rn(0.69314718f);
    const __half2 kC2   = __float2half2_rn(0.24022651f);
    const __half2 kC3   = __float2half2_rn(0.05550411f);
    const __half2 kOne  = __float2half2_rn(1.0f);
    const __half2 kTwo  = __float2half2_rn(2.0f);
    y = pk_max(y, kLo);
    y = pk_min(y, kHi);
    // round to nearest int: t = y + 1536 (ulp=1 in [1024,2048)); bits(t) = 0x6600 + n
    HU t; t.h = __hadd2(y, k1536);
    __half2 nf = __hsub2(t.h, k1536);      // n as f16 (exact)
    __half2 f  = __hsub2(y, nf);           // f in [-0.5, 0.5] (exact, Sterbenz)
    // 2^f, degree-3, rel err ~6e-4
    __half2 p = __hfma2(f, kC3, kC2);
    p = __hfma2(f, p, kC1);
    p = __hfma2(f, p, kOne);
    // 2^n per half: bits(t) = 0x6600 + n; add (0x9A0F - ((15)<<0))... we want
    // (n+15)<<10 per half: (t.u + 0x9A0E9A0F) << 10. Low-half carry into high
    // is guaranteed-absent: n >= -14 so 0x6600+n+0x9A0F >= 0x10001 -> the +1
    // carry from the low half always occurs, pre-subtracted via 0x9A0E.
    HU s; s.u = (t.u + 0x9A0E9A0Fu) << 10; // (n+15)<<10 per half, no cross-talk
    __half2 e = __hmul2(p, s.h);           // 2^y, <= 2^14.5 (no overflow)
    __half2 d = __hadd2(e, kOne);
    // 1/d: magic init (~5% err) + 2 packed Newton iters -> ~f16 eps.
    // bits(d) <= 0x75A8 < 0x7799, so the u32 sub never borrows across halves.
    HU du; du.h = d;
    HU r0; r0.u = 0x77997799u - du.u;
    __half2 r = r0.h;
    __half2 nd = pk_neg(d);
    r = __hmul2(r, __hfma2(nd, r, kTwo));
    r = __hmul2(r, __hfma2(nd, r, kTwo));
    return r;
}

template<int R>
__global__ __launch_bounds__(256) void mlp_kernel(
        const float* __restrict__ x,
        const float* __restrict__ W_in, const float* __restrict__ b_in,
        const float* __restrict__ W_out, const float* __restrict__ b_out,
        const unsigned* __restrict__ wm,
        float* __restrict__ out, int B) {
    const int t = blockIdx.x * blockDim.x + threadIdx.x;
    const int stride = gridDim.x * blockDim.x;

    float wi[8], bi[4];
    #pragma unroll
    for (int k = 0; k < 8; ++k) wi[k] = W_in[k];
    #pragma unroll
    for (int k = 0; k < 4; ++k) bi[k] = b_in[k];

    int rows[R];
    #pragma unroll
    for (int r = 0; r < R; ++r) rows[r] = t + r * stride;

    // stem in fp32, then pack h -> 2x half2 per row
    __half2 h01[R], h23[R];
    #pragma unroll
    for (int r = 0; r < R; ++r) {
        float2 xv = make_float2(0.0f, 0.0f);
        if (rows[r] < B) xv = reinterpret_cast<const float2*>(x)[rows[r]];
        float hh[4];
        #pragma unroll
        for (int j = 0; j < 4; ++j) {
            float v = fmaf(wi[j*2+0], xv.x, fmaf(wi[j*2+1], xv.y, bi[j]));
            hh[j] = fmaxf(v, 0.0f);
        }
        h01[r] = __floats2half2_rn(hh[0], hh[1]);
        h23[r] = __floats2half2_rn(hh[2], hh[3]);
    }

    for (int l = 0; l < NMID; ++l) {
        const unsigned* __restrict__ wl = wm + l * LSTRIDE;  // uniform -> s_load
        HU w[10];
        #pragma unroll
        for (int k = 0; k < 10; ++k) w[k].u = wl[k];
        #pragma unroll
        for (int r = 0; r < R; ++r) {
            __half2 h0b = __half2half2(__low2half (h01[r]));
            __half2 h1b = __half2half2(__high2half(h01[r]));
            __half2 h2b = __half2half2(__low2half (h23[r]));
            __half2 h3b = __half2half2(__high2half(h23[r]));
            __half2 y01 = w[8].h, y23 = w[9].h;   // prescaled biases
            y01 = __hfma2(w[0].h, h0b, y01);
            y01 = __hfma2(w[1].h, h1b, y01);
            y01 = __hfma2(w[2].h, h2b, y01);
            y01 = __hfma2(w[3].h, h3b, y01);
            y23 = __hfma2(w[4].h, h0b, y23);
            y23 = __hfma2(w[5].h, h1b, y23);
            y23 = __hfma2(w[6].h, h2b, y23);
            y23 = __hfma2(w[7].h, h3b, y23);
            h01[r] = sigmoid2_from_y(y01);
            h23[r] = sigmoid2_from_y(y23);
        }
    }

    float wo[4];
    #pragma unroll
    for (int k = 0; k < 4; ++k) wo[k] = W_out[k];
    float bo = b_out[0];
    #pragma unroll
    for (int r = 0; r < R; ++r) {
        float o = fmaf(wo[0], __half2float(__low2half (h01[r])),
                  fmaf(wo[1], __half2float(__high2half(h01[r])),
                  fmaf(wo[2], __half2float(__low2half (h23[r])),
                  fmaf(wo[3], __half2float(__high2half(h23[r])), bo))));
        if (rows[r] < B) out[rows[r]] = o;
    }
}

extern "C" void kernel_launch(void* const* d_in, const int* in_sizes, int n_in,
                              void* d_out, int out_size, void* d_ws, size_t ws_size,
                              hipStream_t stream) {
    const float* x     = (const float*)d_in[0];
    const float* W_in  = (const float*)d_in[1];
    const float* b_in  = (const float*)d_in[2];
    const float* W_mid = (const float*)d_in[3];
    const float* b_mid = (const float*)d_in[4];
    const float* W_out = (const float*)d_in[5];
    const float* b_out = (const float*)d_in[6];
    float* out   = (float*)d_out;
    unsigned* ws = (unsigned*)d_ws;

    const int B = in_sizes[0] / 2;  // x is [B,2]

    hipLaunchKernelGGL(prep_kernel, dim3((NMID * 10 + 255) / 256), dim3(256),
                       0, stream, W_mid, b_mid, ws);

    constexpr int R = 2;
    const int threads = 256;
    const int grid = (B + threads * R - 1) / (threads * R);  // 2048 for B=1M
    hipLaunchKernelGGL((mlp_kernel<R>), dim3(grid), dim3(threads), 0, stream,
                       x, W_in, b_in, W_out, b_out, ws, out, B);
}

// Round 4
// 182.746 us; speedup vs baseline: 1.0672x; 1.0672x over previous
//
#include <hip/hip_runtime.h>
#include <hip/hip_fp16.h>

// MLP_52759378264652: x[B,2] -> Linear(2,4)+ReLU -> 98x(Linear(4,4)+Sigmoid)
//                     -> Linear(4,1). B = 1048576. fp32 in/out.
//
// R1: fp32 + hw trans = exact VALU-issue roofline, 110us (trans = 76% of issue).
// R3: __half2 ocml intrinsics got SCALARIZED (~105 inst/layer-row vs ~50
//     expected) -> 138us. VGPR=12 confirmed long scalar chain.
// R4: same verified math, clang-native ext_vector _Float16 so ops lower
//     straight to v_pk_*_f16; broadcasts via shufflevector (op_sel-foldable);
//     elementwise builtins for pk_max/min. Zero transcendentals.

#define NMID 98
#define LSTRIDE 16  // u32 slots per layer in ws (10 used; 64B-aligned layers)

typedef _Float16 h2 __attribute__((ext_vector_type(2)));
union HU { unsigned u; h2 h; };

__global__ __launch_bounds__(256) void prep_kernel(
        const float* __restrict__ Wm, const float* __restrict__ bm,
        unsigned* __restrict__ ws) {
    int e = blockIdx.x * blockDim.x + threadIdx.x;
    if (e >= NMID * 10) return;
    int l = e / 10;
    int s = e - l * 10;
    const float c = -1.44269504088896340736f;  // -log2(e)
    float lo, hi;
    if (s < 4)       { lo = Wm[l*16 + 0*4 + s];      hi = Wm[l*16 + 1*4 + s]; }
    else if (s < 8)  { int k = s - 4;
                       lo = Wm[l*16 + 2*4 + k];      hi = Wm[l*16 + 3*4 + k]; }
    else if (s == 8) { lo = bm[l*4 + 0];             hi = bm[l*4 + 1]; }
    else             { lo = bm[l*4 + 2];             hi = bm[l*4 + 3]; }
    HU q; q.h = h2{(_Float16)(c * lo), (_Float16)(c * hi)};
    ws[l * LSTRIDE + s] = q.u;
}

// sigmoid pair from prescaled y = -log2(e)*x : returns 1/(1+2^y).
// All full-rate packed ops; math verified on HW in R3 (absmax 0.0).
__device__ __forceinline__ h2 sigmoid2_from_y(h2 y) {
    const h2 kLo   = {(_Float16)-13.5f, (_Float16)-13.5f};
    const h2 kHi   = {(_Float16) 13.5f, (_Float16) 13.5f};
    const h2 k1536 = {(_Float16)1536.0f, (_Float16)1536.0f};
    const h2 kC1   = {(_Float16)0.69314718f, (_Float16)0.69314718f};
    const h2 kC2   = {(_Float16)0.24022651f, (_Float16)0.24022651f};
    const h2 kC3   = {(_Float16)0.05550411f, (_Float16)0.05550411f};
    const h2 kOne  = {(_Float16)1.0f, (_Float16)1.0f};
    const h2 kTwo  = {(_Float16)2.0f, (_Float16)2.0f};
    y = __builtin_elementwise_max(y, kLo);
    y = __builtin_elementwise_min(y, kHi);
    // round-to-int: t = y + 1536 (ulp=1 in [1024,2048)); bits(t) = 0x6600 + n
    HU t; t.h = y + k1536;
    h2 nf = t.h - k1536;        // n as f16, exact
    h2 f  = y - nf;             // f in [-0.5,0.5], exact (Sterbenz)
    // 2^f, degree-3 (rel err ~6e-4)
    h2 p = f * kC3 + kC2;
    p = f * p + kC1;
    p = f * p + kOne;
    // 2^n per half: (t.u + 0x9A0E9A0F)<<10 = (n+15)<<10 per half.
    // n in [-14,14] -> n+15 in [1,29]; low-half carry always occurs
    // (pre-compensated via 0x9A0E) and shifted bits never cross halves.
    HU s; s.u = (t.u + 0x9A0E9A0Fu) << 10;
    h2 e = p * s.h;             // 2^y, <= 2^14.5
    h2 d = e + kOne;
    // 1/d: magic init (~5% err) + 2 packed Newton -> ~f16 eps.
    // bits(d) <= 0x75A8 < 0x7799 -> u32 sub never borrows across halves.
    HU du; du.h = d;
    HU r0; r0.u = 0x77997799u - du.u;
    h2 r = r0.h;
    r = r * (kTwo - d * r);
    r = r * (kTwo - d * r);
    return r;
}

template<int R>
__global__ __launch_bounds__(256) void mlp_kernel(
        const float* __restrict__ x,
        const float* __restrict__ W_in, const float* __restrict__ b_in,
        const float* __restrict__ W_out, const float* __restrict__ b_out,
        const unsigned* __restrict__ wm,
        float* __restrict__ out, int B) {
    const int t = blockIdx.x * blockDim.x + threadIdx.x;
    const int stride = gridDim.x * blockDim.x;

    float wi[8], bi[4];
    #pragma unroll
    for (int k = 0; k < 8; ++k) wi[k] = W_in[k];
    #pragma unroll
    for (int k = 0; k < 4; ++k) bi[k] = b_in[k];

    int rows[R];
    #pragma unroll
    for (int r = 0; r < R; ++r) rows[r] = t + r * stride;

    // stem in fp32, then pack h -> 2x h2 per row
    h2 h01[R], h23[R];
    #pragma unroll
    for (int r = 0; r < R; ++r) {
        float2 xv = make_float2(0.0f, 0.0f);
        if (rows[r] < B) xv = reinterpret_cast<const float2*>(x)[rows[r]];
        float hh[4];
        #pragma unroll
        for (int j = 0; j < 4; ++j) {
            float v = fmaf(wi[j*2+0], xv.x, fmaf(wi[j*2+1], xv.y, bi[j]));
            hh[j] = fmaxf(v, 0.0f);
        }
        h01[r] = h2{(_Float16)hh[0], (_Float16)hh[1]};
        h23[r] = h2{(_Float16)hh[2], (_Float16)hh[3]};
    }

    for (int l = 0; l < NMID; ++l) {
        const unsigned* __restrict__ wl = wm + l * LSTRIDE;  // uniform -> s_load
        HU w[10];
        #pragma unroll
        for (int k = 0; k < 10; ++k) w[k].u = wl[k];
        #pragma unroll
        for (int r = 0; r < R; ++r) {
            h2 b0 = __builtin_shufflevector(h01[r], h01[r], 0, 0);
            h2 b1 = __builtin_shufflevector(h01[r], h01[r], 1, 1);
            h2 b2 = __builtin_shufflevector(h23[r], h23[r], 0, 0);
            h2 b3 = __builtin_shufflevector(h23[r], h23[r], 1, 1);
            h2 y01 = w[8].h;   // prescaled biases
            h2 y23 = w[9].h;
            y01 = w[0].h * b0 + y01;
            y01 = w[1].h * b1 + y01;
            y01 = w[2].h * b2 + y01;
            y01 = w[3].h * b3 + y01;
            y23 = w[4].h * b0 + y23;
            y23 = w[5].h * b1 + y23;
            y23 = w[6].h * b2 + y23;
            y23 = w[7].h * b3 + y23;
            h01[r] = sigmoid2_from_y(y01);
            h23[r] = sigmoid2_from_y(y23);
        }
    }

    float wo[4];
    #pragma unroll
    for (int k = 0; k < 4; ++k) wo[k] = W_out[k];
    float bo = b_out[0];
    #pragma unroll
    for (int r = 0; r < R; ++r) {
        float o = fmaf(wo[0], (float)h01[r].x,
                  fmaf(wo[1], (float)h01[r].y,
                  fmaf(wo[2], (float)h23[r].x,
                  fmaf(wo[3], (float)h23[r].y, bo))));
        if (rows[r] < B) out[rows[r]] = o;
    }
}

extern "C" void kernel_launch(void* const* d_in, const int* in_sizes, int n_in,
                              void* d_out, int out_size, void* d_ws, size_t ws_size,
                              hipStream_t stream) {
    const float* x     = (const float*)d_in[0];
    const float* W_in  = (const float*)d_in[1];
    const float* b_in  = (const float*)d_in[2];
    const float* W_mid = (const float*)d_in[3];
    const float* b_mid = (const float*)d_in[4];
    const float* W_out = (const float*)d_in[5];
    const float* b_out = (const float*)d_in[6];
    float* out   = (float*)d_out;
    unsigned* ws = (unsigned*)d_ws;

    const int B = in_sizes[0] / 2;  // x is [B,2]

    hipLaunchKernelGGL(prep_kernel, dim3((NMID * 10 + 255) / 256), dim3(256),
                       0, stream, W_mid, b_mid, ws);

    constexpr int R = 2;
    const int threads = 256;
    const int grid = (B + threads * R - 1) / (threads * R);  // 2048 for B=1M
    hipLaunchKernelGGL((mlp_kernel<R>), dim3(grid), dim3(threads), 0, stream,
                       x, W_in, b_in, W_out, b_out, ws, out, B);
}